// Round 5
// baseline (324.712 us; speedup 1.0000x reference)
//
#include <hip/hip_runtime.h>

// AmpLoss: 10 global reductions (5 mask counts + 5 masked smape-sums) over
// B=2^24 fp32 samples, O(1) finalize as separate dispatch (kernel boundary =
// coherence; per-block __threadfence regressed 2.5x in an early round).
//
// Round-8: loop-shape probe. Burst-unroll gradient is dead (QPT4conf:116,
// QPT8:100, QPT16:135) and the model says we should saturate HBM but sit at
// 4.4 B/cy/CU with occupancy ~18%. Proven-fast streaming kernels (copy 6.3
// TB/s, RMSNorm 4.9 TB/s) use lean ROLLED loops + max waves/SIMD, not giant
// register bursts. Single change: QPT=8 restructured as `#pragma unroll 1`
// outer loop (4 iters x 2 quads = 8 loads/iter, ~32 VGPR payload) +
// __launch_bounds__(256, 8) to force VGPR<=64 -> 8 waves/SIMD allocatable.
// Grid (2048x256), tail (unique-row store, no memset, parallel finalize)
// unchanged from the 315 us best.

#define B_TOTAL 16777216
#define NBLOCKS 2048
#define NTHREADS 256
#define NQUADS (B_TOTAL / 4)          // 4194304
#define STRIDE (NBLOCKS * NTHREADS)   // 524288 threads -> 8 quads/thread
#define QPT (NQUADS / STRIDE)         // 8
#define NSETS 8                       // atomic-fallback slot sets

typedef float vf4 __attribute__((ext_vector_type(4)));  // clang-native vector

__device__ __forceinline__ float rcp_fast(float x) {
    return __builtin_amdgcn_rcpf(x);  // v_rcp_f32, ~1 ulp (bit-identical vs ref here)
}

__device__ __forceinline__ void proc4(vf4 dp, vf4 sp, vf4 dv, vf4 sv,
                                      float (&sum)[5], int (&cnt)[5]) {
    #pragma unroll
    for (int j = 0; j < 4; ++j) {
        float s = sv[j], d = dv[j];
        bool lt120 = s < 120.0f, lt130 = s < 130.0f, lt140 = s < 140.0f;
        bool dlt80 = d < 80.0f,  dlt90 = d < 90.0f;
        bool normal = lt120 && dlt80;
        bool ne     = lt130 && dlt80;                    // normal | elevated
        bool elevated = ne && !normal;
        bool h1 = ((lt140 && !lt130) || (dlt90 && !dlt80)) && !ne;
        bool h2 = (!lt140 || !dlt90) && !ne && !h1;
        bool crisis = (s > 180.0f) || (d > 120.0f);

        // targets d,s strictly positive -> |d|=d, |s|=s (identical value to ref)
        float pe = 2.0f * (fabsf(dp[j] - d) * rcp_fast(fabsf(dp[j]) + d) +
                           fabsf(sp[j] - s) * rcp_fast(fabsf(sp[j]) + s));

        sum[0] += normal   ? pe : 0.0f;  cnt[0] += normal;
        sum[1] += elevated ? pe : 0.0f;  cnt[1] += elevated;
        sum[2] += h1       ? pe : 0.0f;  cnt[2] += h1;
        sum[3] += h2       ? pe : 0.0f;  cnt[3] += h2;
        sum[4] += crisis   ? pe : 0.0f;  cnt[4] += crisis;
    }
}

// Streams the inputs and leaves per-block partials in ss/cc. Shared by tails.
__device__ __forceinline__ void stream_and_reduce(const float* __restrict__ dbp,
                                                  const float* __restrict__ sbp,
                                                  const float* __restrict__ dt,
                                                  const float* __restrict__ st,
                                                  double (&ss)[5], double (&cc)[5])
{
    float sum[5] = {0.f, 0.f, 0.f, 0.f, 0.f};
    int   cnt[5] = {0, 0, 0, 0, 0};

    const int q0 = blockIdx.x * NTHREADS + threadIdx.x;
    const vf4* __restrict__ pA = (const vf4*)dbp + q0;
    const vf4* __restrict__ pB = (const vf4*)sbp + q0;
    const vf4* __restrict__ pC = (const vf4*)dt  + q0;
    const vf4* __restrict__ pE = (const vf4*)st  + q0;

    // Lean rolled loop: 8 loads (2 quads x 4 streams) per iteration, low VGPR,
    // latency hidden by 8 co-resident waves/SIMD, not per-wave register bursts.
    #pragma unroll 1
    for (int c = 0; c < QPT / 2; ++c) {
        vf4 a0 = pA[0], a1 = pA[STRIDE];
        vf4 b0 = pB[0], b1 = pB[STRIDE];
        vf4 c0 = pC[0], c1 = pC[STRIDE];
        vf4 e0 = pE[0], e1 = pE[STRIDE];
        proc4(a0, b0, c0, e0, sum, cnt);
        proc4(a1, b1, c1, e1, sum, cnt);
        pA += 2 * STRIDE; pB += 2 * STRIDE; pC += 2 * STRIDE; pE += 2 * STRIDE;
    }

    // wave-level butterfly reduce (wave = 64)
    #pragma unroll
    for (int off = 32; off > 0; off >>= 1) {
        #pragma unroll
        for (int k = 0; k < 5; ++k) {
            sum[k] += __shfl_down(sum[k], off);
            cnt[k] += __shfl_down(cnt[k], off);
        }
    }

    __shared__ float s_sum[5][NTHREADS / 64];
    __shared__ int   s_cnt[5][NTHREADS / 64];
    const int lane = threadIdx.x & 63;
    const int wid  = threadIdx.x >> 6;
    if (lane == 0) {
        #pragma unroll
        for (int k = 0; k < 5; ++k) { s_sum[k][wid] = sum[k]; s_cnt[k][wid] = cnt[k]; }
    }
    __syncthreads();

    #pragma unroll
    for (int k = 0; k < 5; ++k) {
        double a = 0.0, b = 0.0;
        #pragma unroll
        for (int w = 0; w < NTHREADS / 64; ++w) {
            a += (double)s_sum[k][w];
            b += (double)s_cnt[k][w];
        }
        ss[k] = a; cc[k] = b;
    }
}

// ---------- store path (preferred): unique row per block, no atomics ----------
__global__ __launch_bounds__(NTHREADS, 8)   // force VGPR<=64 -> 8 waves/SIMD
void amploss_reduce_store(const float* __restrict__ dbp,
                          const float* __restrict__ sbp,
                          const float* __restrict__ dt,
                          const float* __restrict__ st,
                          double* __restrict__ ws)
{
    double ss[5], cc[5];
    stream_and_reduce(dbp, sbp, dt, st, ss, cc);
    if (threadIdx.x == 0) {
        double* row = ws + (size_t)blockIdx.x * 10;
        #pragma unroll
        for (int k = 0; k < 5; ++k) { row[k] = ss[k]; row[5 + k] = cc[k]; }
    }
}

__device__ __forceinline__ void epilogue(const double (&S)[5], const double (&C)[5],
                                         float* __restrict__ out)
{
    double rst = 0.0, m_rst = 0.0, mask_cnt = 0.0;
    for (int k = 0; k < 5; ++k) {
        double c = C[k];
        // match reference's fp32 weight: sqrt(log(batchN / max(cnt,1)))
        float w = sqrtf(logf((float)B_TOTAL / fmaxf((float)c, 1.0f)));
        double Sw = S[k] * (double)w;
        if (c > 0.0) {
            m_rst = (m_rst + Sw) / c / 2.0;
            rst += m_rst;
            mask_cnt += 1.0;
        }
    }
    double r = (mask_cnt == 0.0) ? (rst / 5.0) : (rst / mask_cnt);
    out[0] = (float)r;
}

__global__ __launch_bounds__(NTHREADS)
void amploss_finalize_store(const double* __restrict__ ws, float* __restrict__ out)
{
    __shared__ double part[NTHREADS][10];
    double loc[10];
    #pragma unroll
    for (int k = 0; k < 10; ++k) loc[k] = 0.0;
    for (int r = threadIdx.x; r < NBLOCKS; r += NTHREADS) {
        const double* row = ws + (size_t)r * 10;
        #pragma unroll
        for (int k = 0; k < 10; ++k) loc[k] += row[k];
    }
    #pragma unroll
    for (int k = 0; k < 10; ++k) part[threadIdx.x][k] = loc[k];
    __syncthreads();
    for (int off = NTHREADS / 2; off > 0; off >>= 1) {
        if (threadIdx.x < off) {
            #pragma unroll
            for (int k = 0; k < 10; ++k)
                part[threadIdx.x][k] += part[threadIdx.x + off][k];
        }
        __syncthreads();
    }
    if (threadIdx.x == 0) {
        double S[5], C[5];
        #pragma unroll
        for (int k = 0; k < 5; ++k) { S[k] = part[0][k]; C[k] = part[0][5 + k]; }
        epilogue(S, C, out);
    }
}

// ---------- atomic fallback (previous passing version) ----------
__global__ __launch_bounds__(NTHREADS)
void amploss_reduce_atomic(const float* __restrict__ dbp,
                           const float* __restrict__ sbp,
                           const float* __restrict__ dt,
                           const float* __restrict__ st,
                           double* __restrict__ ws)
{
    double ss[5], cc[5];
    stream_and_reduce(dbp, sbp, dt, st, ss, cc);
    if (threadIdx.x == 0) {
        const int base = (blockIdx.x & (NSETS - 1)) * 10;
        #pragma unroll
        for (int k = 0; k < 5; ++k) {
            atomicAdd(&ws[base + k], ss[k]);
            atomicAdd(&ws[base + 5 + k], cc[k]);
        }
    }
}

__global__ void amploss_finalize_atomic(const double* __restrict__ ws, float* __restrict__ out)
{
    if (threadIdx.x != 0 || blockIdx.x != 0) return;
    double S[5], C[5];
    for (int k = 0; k < 5; ++k) { S[k] = 0.0; C[k] = 0.0; }
    for (int st = 0; st < NSETS; ++st)
        for (int k = 0; k < 5; ++k) {
            S[k] += ws[st * 10 + k];
            C[k] += ws[st * 10 + 5 + k];
        }
    epilogue(S, C, out);
}

extern "C" void kernel_launch(void* const* d_in, const int* in_sizes, int n_in,
                              void* d_out, int out_size, void* d_ws, size_t ws_size,
                              hipStream_t stream) {
    // setup_inputs order: dbp_pred, sbp_pred, mbp_pred(unused), d, s, m(unused)
    const float* dbp = (const float*)d_in[0];
    const float* sbp = (const float*)d_in[1];
    const float* dt  = (const float*)d_in[3];
    const float* st  = (const float*)d_in[4];
    float* out = (float*)d_out;
    double* ws = (double*)d_ws;

    const size_t need_store = (size_t)NBLOCKS * 10 * sizeof(double);  // 160 KB
    if (ws_size >= need_store) {
        // no memset needed: every ws row is overwritten by exactly one block
        amploss_reduce_store<<<NBLOCKS, NTHREADS, 0, stream>>>(dbp, sbp, dt, st, ws);
        amploss_finalize_store<<<1, NTHREADS, 0, stream>>>(ws, out);
    } else {
        (void)hipMemsetAsync(ws, 0, NSETS * 10 * sizeof(double), stream);
        amploss_reduce_atomic<<<NBLOCKS, NTHREADS, 0, stream>>>(dbp, sbp, dt, st, ws);
        amploss_finalize_atomic<<<1, 64, 0, stream>>>(ws, out);
    }
}

// Round 6
// 294.153 us; speedup vs baseline: 1.1039x; 1.1039x over previous
//
#include <hip/hip_runtime.h>

// AmpLoss: 10 global reductions (5 mask counts + 5 masked smape-sums) over
// B=2^24 fp32 samples, O(1) finalize as separate dispatch (kernel boundary =
// coherence; per-block __threadfence regressed 2.5x in an early round).
//
// Round-9: cache-path probe. Evidence: reduce pinned at ~100 us / 2.7 TB/s
// delivered across burst-VGPR88-occ18%, burst-VGPR128, rolled-VGPR32-occ60%;
// zero-HBM-fetch iterations (fully L3-served) ALSO 100 us. Shape, ILP, TLP,
// occupancy, hit-mix all exonerated -> the delivery path (memory-side L3)
// looks like the cap. Single change vs the round-8 kernel: nontemporal loads
// (MUBUF nt: no cache allocation, straight HBM path) on the proven shape.
// FETCH_SIZE must jump 131->~262 MB if nt took effect.

#define B_TOTAL 16777216
#define NBLOCKS 2048
#define NTHREADS 256
#define NQUADS (B_TOTAL / 4)          // 4194304
#define STRIDE (NBLOCKS * NTHREADS)   // 524288 threads -> 8 quads/thread
#define QPT (NQUADS / STRIDE)         // 8
#define NSETS 8                       // atomic-fallback slot sets

typedef float vf4 __attribute__((ext_vector_type(4)));  // clang-native vector

__device__ __forceinline__ float rcp_fast(float x) {
    return __builtin_amdgcn_rcpf(x);  // v_rcp_f32, ~1 ulp (bit-identical vs ref here)
}

__device__ __forceinline__ void proc4(vf4 dp, vf4 sp, vf4 dv, vf4 sv,
                                      float (&sum)[5], int (&cnt)[5]) {
    #pragma unroll
    for (int j = 0; j < 4; ++j) {
        float s = sv[j], d = dv[j];
        bool lt120 = s < 120.0f, lt130 = s < 130.0f, lt140 = s < 140.0f;
        bool dlt80 = d < 80.0f,  dlt90 = d < 90.0f;
        bool normal = lt120 && dlt80;
        bool ne     = lt130 && dlt80;                    // normal | elevated
        bool elevated = ne && !normal;
        bool h1 = ((lt140 && !lt130) || (dlt90 && !dlt80)) && !ne;
        bool h2 = (!lt140 || !dlt90) && !ne && !h1;
        bool crisis = (s > 180.0f) || (d > 120.0f);

        // targets d,s strictly positive -> |d|=d, |s|=s (identical value to ref)
        float pe = 2.0f * (fabsf(dp[j] - d) * rcp_fast(fabsf(dp[j]) + d) +
                           fabsf(sp[j] - s) * rcp_fast(fabsf(sp[j]) + s));

        sum[0] += normal   ? pe : 0.0f;  cnt[0] += normal;
        sum[1] += elevated ? pe : 0.0f;  cnt[1] += elevated;
        sum[2] += h1       ? pe : 0.0f;  cnt[2] += h1;
        sum[3] += h2       ? pe : 0.0f;  cnt[3] += h2;
        sum[4] += crisis   ? pe : 0.0f;  cnt[4] += crisis;
    }
}

// Streams the inputs and leaves per-block partials in ss/cc. Shared by tails.
__device__ __forceinline__ void stream_and_reduce(const float* __restrict__ dbp,
                                                  const float* __restrict__ sbp,
                                                  const float* __restrict__ dt,
                                                  const float* __restrict__ st,
                                                  double (&ss)[5], double (&cc)[5])
{
    float sum[5] = {0.f, 0.f, 0.f, 0.f, 0.f};
    int   cnt[5] = {0, 0, 0, 0, 0};

    const int q0 = blockIdx.x * NTHREADS + threadIdx.x;
    const vf4* __restrict__ pA = (const vf4*)dbp + q0;
    const vf4* __restrict__ pB = (const vf4*)sbp + q0;
    const vf4* __restrict__ pC = (const vf4*)dt  + q0;
    const vf4* __restrict__ pE = (const vf4*)st  + q0;

    // Lean rolled loop (proven 100us shape), nontemporal: bypass L2/L3
    // allocation -> probes whether the memory-side cache path is the 2.7 TB/s cap.
    #pragma unroll 1
    for (int c = 0; c < QPT / 2; ++c) {
        vf4 a0 = __builtin_nontemporal_load(pA);
        vf4 a1 = __builtin_nontemporal_load(pA + STRIDE);
        vf4 b0 = __builtin_nontemporal_load(pB);
        vf4 b1 = __builtin_nontemporal_load(pB + STRIDE);
        vf4 c0 = __builtin_nontemporal_load(pC);
        vf4 c1 = __builtin_nontemporal_load(pC + STRIDE);
        vf4 e0 = __builtin_nontemporal_load(pE);
        vf4 e1 = __builtin_nontemporal_load(pE + STRIDE);
        proc4(a0, b0, c0, e0, sum, cnt);
        proc4(a1, b1, c1, e1, sum, cnt);
        pA += 2 * STRIDE; pB += 2 * STRIDE; pC += 2 * STRIDE; pE += 2 * STRIDE;
    }

    // wave-level butterfly reduce (wave = 64)
    #pragma unroll
    for (int off = 32; off > 0; off >>= 1) {
        #pragma unroll
        for (int k = 0; k < 5; ++k) {
            sum[k] += __shfl_down(sum[k], off);
            cnt[k] += __shfl_down(cnt[k], off);
        }
    }

    __shared__ float s_sum[5][NTHREADS / 64];
    __shared__ int   s_cnt[5][NTHREADS / 64];
    const int lane = threadIdx.x & 63;
    const int wid  = threadIdx.x >> 6;
    if (lane == 0) {
        #pragma unroll
        for (int k = 0; k < 5; ++k) { s_sum[k][wid] = sum[k]; s_cnt[k][wid] = cnt[k]; }
    }
    __syncthreads();

    #pragma unroll
    for (int k = 0; k < 5; ++k) {
        double a = 0.0, b = 0.0;
        #pragma unroll
        for (int w = 0; w < NTHREADS / 64; ++w) {
            a += (double)s_sum[k][w];
            b += (double)s_cnt[k][w];
        }
        ss[k] = a; cc[k] = b;
    }
}

// ---------- store path (preferred): unique row per block, no atomics ----------
__global__ __launch_bounds__(NTHREADS, 8)   // force VGPR<=64 -> 8 waves/SIMD
void amploss_reduce_store(const float* __restrict__ dbp,
                          const float* __restrict__ sbp,
                          const float* __restrict__ dt,
                          const float* __restrict__ st,
                          double* __restrict__ ws)
{
    double ss[5], cc[5];
    stream_and_reduce(dbp, sbp, dt, st, ss, cc);
    if (threadIdx.x == 0) {
        double* row = ws + (size_t)blockIdx.x * 10;
        #pragma unroll
        for (int k = 0; k < 5; ++k) { row[k] = ss[k]; row[5 + k] = cc[k]; }
    }
}

__device__ __forceinline__ void epilogue(const double (&S)[5], const double (&C)[5],
                                         float* __restrict__ out)
{
    double rst = 0.0, m_rst = 0.0, mask_cnt = 0.0;
    for (int k = 0; k < 5; ++k) {
        double c = C[k];
        // match reference's fp32 weight: sqrt(log(batchN / max(cnt,1)))
        float w = sqrtf(logf((float)B_TOTAL / fmaxf((float)c, 1.0f)));
        double Sw = S[k] * (double)w;
        if (c > 0.0) {
            m_rst = (m_rst + Sw) / c / 2.0;
            rst += m_rst;
            mask_cnt += 1.0;
        }
    }
    double r = (mask_cnt == 0.0) ? (rst / 5.0) : (rst / mask_cnt);
    out[0] = (float)r;
}

__global__ __launch_bounds__(NTHREADS)
void amploss_finalize_store(const double* __restrict__ ws, float* __restrict__ out)
{
    __shared__ double part[NTHREADS][10];
    double loc[10];
    #pragma unroll
    for (int k = 0; k < 10; ++k) loc[k] = 0.0;
    for (int r = threadIdx.x; r < NBLOCKS; r += NTHREADS) {
        const double* row = ws + (size_t)r * 10;
        #pragma unroll
        for (int k = 0; k < 10; ++k) loc[k] += row[k];
    }
    #pragma unroll
    for (int k = 0; k < 10; ++k) part[threadIdx.x][k] = loc[k];
    __syncthreads();
    for (int off = NTHREADS / 2; off > 0; off >>= 1) {
        if (threadIdx.x < off) {
            #pragma unroll
            for (int k = 0; k < 10; ++k)
                part[threadIdx.x][k] += part[threadIdx.x + off][k];
        }
        __syncthreads();
    }
    if (threadIdx.x == 0) {
        double S[5], C[5];
        #pragma unroll
        for (int k = 0; k < 5; ++k) { S[k] = part[0][k]; C[k] = part[0][5 + k]; }
        epilogue(S, C, out);
    }
}

// ---------- atomic fallback (previous passing version) ----------
__global__ __launch_bounds__(NTHREADS)
void amploss_reduce_atomic(const float* __restrict__ dbp,
                           const float* __restrict__ sbp,
                           const float* __restrict__ dt,
                           const float* __restrict__ st,
                           double* __restrict__ ws)
{
    double ss[5], cc[5];
    stream_and_reduce(dbp, sbp, dt, st, ss, cc);
    if (threadIdx.x == 0) {
        const int base = (blockIdx.x & (NSETS - 1)) * 10;
        #pragma unroll
        for (int k = 0; k < 5; ++k) {
            atomicAdd(&ws[base + k], ss[k]);
            atomicAdd(&ws[base + 5 + k], cc[k]);
        }
    }
}

__global__ void amploss_finalize_atomic(const double* __restrict__ ws, float* __restrict__ out)
{
    if (threadIdx.x != 0 || blockIdx.x != 0) return;
    double S[5], C[5];
    for (int k = 0; k < 5; ++k) { S[k] = 0.0; C[k] = 0.0; }
    for (int st = 0; st < NSETS; ++st)
        for (int k = 0; k < 5; ++k) {
            S[k] += ws[st * 10 + k];
            C[k] += ws[st * 10 + 5 + k];
        }
    epilogue(S, C, out);
}

extern "C" void kernel_launch(void* const* d_in, const int* in_sizes, int n_in,
                              void* d_out, int out_size, void* d_ws, size_t ws_size,
                              hipStream_t stream) {
    // setup_inputs order: dbp_pred, sbp_pred, mbp_pred(unused), d, s, m(unused)
    const float* dbp = (const float*)d_in[0];
    const float* sbp = (const float*)d_in[1];
    const float* dt  = (const float*)d_in[3];
    const float* st  = (const float*)d_in[4];
    float* out = (float*)d_out;
    double* ws = (double*)d_ws;

    const size_t need_store = (size_t)NBLOCKS * 10 * sizeof(double);  // 160 KB
    if (ws_size >= need_store) {
        // no memset needed: every ws row is overwritten by exactly one block
        amploss_reduce_store<<<NBLOCKS, NTHREADS, 0, stream>>>(dbp, sbp, dt, st, ws);
        amploss_finalize_store<<<1, NTHREADS, 0, stream>>>(ws, out);
    } else {
        (void)hipMemsetAsync(ws, 0, NSETS * 10 * sizeof(double), stream);
        amploss_reduce_atomic<<<NBLOCKS, NTHREADS, 0, stream>>>(dbp, sbp, dt, st, ws);
        amploss_finalize_atomic<<<1, 64, 0, stream>>>(ws, out);
    }
}